// Round 1
// baseline (3867.294 us; speedup 1.0000x reference)
//
#include <hip/hip_runtime.h>
#include <math.h>

// ---------------------------------------------------------------------------
// FNO_multi: B=4, V=3, S=256x256, TIN=10, WIDTH=32, M1=M2=16, NL=6, VOUT=3, STEP=10
// Strategy: rfft2/irfft2 replaced by truncated DFT matmuls (only 32x16 modes used).
// All fp32. Layout for activations: [B][C=32][V][256][256].
// ---------------------------------------------------------------------------

#define ACT   25165824    // 4*32*3*256*256 floats
#define TSZ   3145728     // 4*32*3*256*32
#define XFSZ  393216      // 4*3*32*32*16*2
#define OFF_A   0
#define OFF_B   25165824
#define OFF_T   50331648
#define OFF_XF  53477376
#define OFF_O   53870592
#define OFF_T1  54263808  // tab1T [m=256][o=32]  (o=2k: cos, o=2k+1: -sin)
#define OFF_T2T 54272000  // tab2  [n=256][kx=32][2] = (cos, sin)
#define OFF_TAC 54288384  // tabA_c [kx=32][n=256]
#define OFF_TAS 54296576  // tabA_s [kx=32][n=256]
#define OFF_TB  54304768  // tabB  [j=32][m=256]  (scaled inverse-y table)
// end = 54312960 floats = 217,251,840 bytes of ws

__device__ __forceinline__ float geluf(float x) {
    return 0.5f * x * (1.0f + erff(x * 0.70710678118654752f));
}

__global__ void k_init_tables(float* __restrict__ ws) {
    const float W0 = 6.2831853071795864769f / 256.0f;
    int stride = gridDim.x * blockDim.x;
    int tid = blockIdx.x * blockDim.x + threadIdx.x;
    for (int idx = tid; idx < 8192; idx += stride) {   // tab1T
        int m = idx >> 5, o = idx & 31, k = o >> 1;
        float th = W0 * (float)((k * m) & 255);
        ws[OFF_T1 + idx] = (o & 1) ? -sinf(th) : cosf(th);
    }
    for (int idx = tid; idx < 8192; idx += stride) {   // tab2
        int n = idx >> 5, kx = idx & 31;
        int KX = (kx < 16) ? kx : (kx + 224);
        float th = W0 * (float)((KX * n) & 255);
        ws[OFF_T2T + 2*idx]     = cosf(th);
        ws[OFF_T2T + 2*idx + 1] = sinf(th);
    }
    for (int idx = tid; idx < 8192; idx += stride) {   // tabA
        int kx = idx >> 8, n = idx & 255;
        int KX = (kx < 16) ? kx : (kx + 224);
        float th = W0 * (float)((KX * n) & 255);
        ws[OFF_TAC + idx] = cosf(th);
        ws[OFF_TAS + idx] = sinf(th);
    }
    for (int idx = tid; idx < 8192; idx += stride) {   // tabB
        int j = idx >> 8, m = idx & 255, k = j >> 1;
        float th = W0 * (float)((k * m) & 255);
        float beta = (k == 0) ? (1.0f/65536.0f) : (2.0f/65536.0f);
        float val;
        if (j & 1) val = (k == 0) ? 0.0f : -beta * sinf(th);
        else       val = beta * cosf(th);
        ws[OFF_TB + idx] = val;
    }
}

// fc0: h[b,c,v,n,m] = sum_t x[b,v,n,m,t]*w[t,c] + gx*w[10,c] + gy*w[11,c] + b[c]
__global__ __launch_bounds__(256) void k_fc0(const float* __restrict__ x,
                                             const float* __restrict__ w,
                                             const float* __restrict__ bias,
                                             float* __restrict__ outA) {
    int blk = blockIdx.x;           // (b*3+v)*256 + n
    int m = threadIdx.x;
    int n = blk & 255;
    int bv = blk >> 8;
    int v = bv % 3, b = bv / 3;
    const float* xp = x + ((size_t)blk * 256 + m) * 10;
    float xin[10];
#pragma unroll
    for (int t = 0; t < 10; t++) xin[t] = xp[t];
    float gx = (float)n * (1.0f/255.0f), gy = (float)m * (1.0f/255.0f);
    float* op = outA + ((size_t)(b*96) + v) * 65536 + n * 256 + m;
#pragma unroll
    for (int c = 0; c < 32; c++) {
        float a = bias[c] + gx * w[10*32 + c] + gy * w[11*32 + c];
#pragma unroll
        for (int t = 0; t < 10; t++) a += xin[t] * w[t*32 + c];
        op[(size_t)c * 196608] = a;
    }
}

// stage 1: y-DFT. rows = (b,c,v,n) flattened. T[row][o] = sum_m IN[row][m]*tab1[m][o]
__global__ __launch_bounds__(256) void k_dft_y(const float* __restrict__ IN,
                                               float* __restrict__ T,
                                               const float* __restrict__ tab1) {
    __shared__ float lds[32*257];
    int rowbase = blockIdx.x * 32;
    int tid = threadIdx.x;
#pragma unroll 4
    for (int i = 0; i < 32; i++)
        lds[i*257 + tid] = IN[(size_t)(rowbase + i) * 256 + tid];
    __syncthreads();
    int r = tid >> 3, og = tid & 7;
    const float* tb = tab1 + og * 4;
    const float* xr = lds + r * 257;
    float a0 = 0.f, a1 = 0.f, a2 = 0.f, a3 = 0.f;
#pragma unroll 4
    for (int m = 0; m < 256; m++) {
        float xv = xr[m];
        float4 t = *(const float4*)(tb + m * 32);
        a0 += xv * t.x; a1 += xv * t.y; a2 += xv * t.z; a3 += xv * t.w;
    }
    float4 res; res.x = a0; res.y = a1; res.z = a2; res.w = a3;
    *(float4*)(T + (size_t)(rowbase + r) * 32 + og * 4) = res;
}

// stage 2: x-DFT. XF[(bv*32+i)*1024 + (kx*16+ky)*2 + ri]
__global__ __launch_bounds__(256) void k_dft_x(const float* __restrict__ T,
                                               float* __restrict__ XF,
                                               const float* __restrict__ tab2) {
    int blk = blockIdx.x;            // bv*32 + i
    int i = blk & 31; int bv = blk >> 5;
    int b = bv / 3, v = bv - 3*b;
    int tid = threadIdx.x;
    int ky = tid & 15, kxh = tid >> 4;   // kxh in 0..15, handles kx=kxh and kxh+16
    const float* tp = T + (size_t)((b*32 + i)*3 + v) * 8192 + 2*ky;
    float r0=0.f, i0=0.f, r1=0.f, i1=0.f;
#pragma unroll 2
    for (int n = 0; n < 256; n++) {
        float tr = tp[n*32], ti = tp[n*32 + 1];
        float2 cs0 = *(const float2*)(tab2 + n*64 + kxh*2);
        float2 cs1 = *(const float2*)(tab2 + n*64 + (kxh+16)*2);
        r0 += tr*cs0.x + ti*cs0.y;  i0 += ti*cs0.x - tr*cs0.y;
        r1 += tr*cs1.x + ti*cs1.y;  i1 += ti*cs1.x - tr*cs1.y;
    }
    float2* xfp = (float2*)(XF + (size_t)blk * 1024);
    float2 v0; v0.x = r0; v0.y = i0;
    float2 v1; v1.x = r1; v1.y = i1;
    xfp[kxh*16 + ky] = v0;
    xfp[(kxh+16)*16 + ky] = v1;
}

// complex channel mix: O[bv*32+o][kx][ky] = sum_i XF[bv*32+i][kx][ky] * W[i][o]
__global__ __launch_bounds__(256) void k_mix(const float* __restrict__ XF,
                                             float* __restrict__ O,
                                             const float* __restrict__ w1r,
                                             const float* __restrict__ w1i,
                                             const float* __restrict__ w2r,
                                             const float* __restrict__ w2i, int l) {
    int blk = blockIdx.x;            // bv*32 + o
    int o = blk & 31; int bv = blk >> 5;
    int b = bv / 3, v = bv - 3*b;
    int tid = threadIdx.x;
    int ky = tid & 15, kxh = tid >> 4;
    float R0=0.f, I0=0.f, R1=0.f, I1=0.f;
#pragma unroll
    for (int i = 0; i < 32; i++) {
        const float2* xfp = (const float2*)(XF + (size_t)(bv*32 + i) * 1024);
        float2 xf0 = xfp[kxh*16 + ky];
        float2 xf1 = xfp[(kxh+16)*16 + ky];
        size_t wbase = ((size_t)((l*32 + i)*32 + o)*3 + v) * 256;
        float a1r = w1r[wbase + kxh*16 + ky], a1i = w1i[wbase + kxh*16 + ky];
        float a2r = w2r[wbase + kxh*16 + ky], a2i = w2i[wbase + kxh*16 + ky];
        R0 += xf0.x*a1r - xf0.y*a1i;  I0 += xf0.x*a1i + xf0.y*a1r;
        R1 += xf1.x*a2r - xf1.y*a2i;  I1 += xf1.x*a2i + xf1.y*a2r;
    }
    float2* op = (float2*)(O + (size_t)blk * 1024);
    float2 v0; v0.x = R0; v0.y = I0;
    float2 v1; v1.x = R1; v1.y = I1;
    op[kxh*16 + ky] = v0;
    op[(kxh+16)*16 + ky] = v1;
}

// inverse x-DFT: T2[b][o][v][n][2k+ri] = sum_kx O[..][kx][k] * e^{+2pi i kx n/256}
__global__ __launch_bounds__(256) void k_idft_x(const float* __restrict__ O,
                                                float* __restrict__ T2,
                                                const float* __restrict__ tac,
                                                const float* __restrict__ tas) {
    int blk = blockIdx.x;            // bv*32 + o
    int o = blk & 31; int bv = blk >> 5;
    int b = bv / 3, v = bv - 3*b;
    int tid = threadIdx.x;
    int ky2 = tid & 31, n8 = tid >> 5;
    int ky = ky2 >> 1, ri = ky2 & 1;
    const float2* op = (const float2*)(O + (size_t)blk * 1024);
    float* t2p = T2 + (size_t)((b*32 + o)*3 + v) * 8192;
#pragma unroll 2
    for (int ii = 0; ii < 32; ii++) {
        int n = ii*8 + n8;
        float acc = 0.f;
#pragma unroll
        for (int kx = 0; kx < 32; kx++) {
            float2 ov = op[kx*16 + ky];
            float c = tac[kx*256 + n], s = tas[kx*256 + n];
            float ca = ri ? s : c;
            float cb = ri ? c : -s;
            acc += ov.x*ca + ov.y*cb;
        }
        t2p[n*32 + ky2] = acc;
    }
}

// fused inverse y-DFT + conv block. One block per (b,v,n) row; thread = column m.
// x1[c] (spectral output) lives in registers; T2 + weights read as scalars.
// NOTE: IN/OUT/SK may alias (in-place layers) -> no __restrict__ on them.
template<int HAS_SKIP>
__global__ __launch_bounds__(256) void k_conv(
    const float* IN, float* OUT, const float* SK,
    const float* __restrict__ T2, const float* __restrict__ tabB,
    const float* __restrict__ m1w, const float* __restrict__ m1b,
    const float* __restrict__ m2w, const float* __restrict__ m2b,
    const float* __restrict__ ww,  const float* __restrict__ wb,
    const float* __restrict__ bw,  const float* __restrict__ bb, int l)
{
    int blk = blockIdx.x;            // (b*3+v)*256 + n
    int m = threadIdx.x;
    int n = blk & 255; int bv = blk >> 8;
    int b = bv / 3, v = bv - 3*b;

    // ---- inverse y-DFT: x1[c] = sum_j T2[b,c,v,n,j] * tabB[j][m]
    float tb[32];
#pragma unroll
    for (int j = 0; j < 32; j++) tb[j] = tabB[j*256 + m];
    const float* t2p = T2 + (size_t)(b*96 + v) * 8192 + n * 32;
    float x1[32];
#pragma unroll
    for (int c = 0; c < 32; c++) {
        const float* tp = t2p + c * 24576;
        float a = 0.f;
#pragma unroll
        for (int j = 0; j < 32; j++) a += tp[j] * tb[j];
        x1[c] = a;
    }

    // ---- conv m1 + gelu
    const float* m1wl = m1w + l*1024; const float* m1bl = m1b + l*32;
    float g1[32];
#pragma unroll
    for (int o = 0; o < 32; o++) {
        float a = m1bl[o];
#pragma unroll
        for (int c = 0; c < 32; c++) a += m1wl[o*32 + c] * x1[c];
        g1[o] = geluf(a);
    }

    // ---- load h (for x2 path)
    const float* inp = IN + (size_t)(b*96 + v) * 65536 + n * 256 + m;
    float hv[32];
#pragma unroll
    for (int c = 0; c < 32; c++) hv[c] = inp[(size_t)c * 196608];

    const float* m2wl = m2w + l*1024; const float* m2bl = m2b + l*32;
    const float* wwl  = ww  + l*1024; const float* wbl  = wb  + l*32;
    const float* bwl  = bw  + l*64;   const float* bbl  = bb  + l*32;
    float gx = (float)n * (1.0f/255.0f), gy = (float)m * (1.0f/255.0f);
    float* outp = OUT + (size_t)(b*96 + v) * 65536 + n * 256 + m;
    const float* skp = SK + (size_t)(b*96 + v) * 65536 + n * 256 + m;

#pragma unroll
    for (int o = 0; o < 32; o++) {
        float a = m2bl[o] + wbl[o] + bbl[o] + bwl[o*2]*gx + bwl[o*2+1]*gy;
#pragma unroll
        for (int c = 0; c < 32; c++) a += m2wl[o*32 + c] * g1[c];
#pragma unroll
        for (int c = 0; c < 32; c++) a += wwl[o*32 + c] * hv[c];
        float val = geluf(a);
        if (HAS_SKIP) val += skp[(size_t)o * 196608];
        outp[(size_t)o * 196608] = val;
    }
}

// final: fc1v (v->vout, gelu) -> fc1t (32->256, gelu) -> fc2t (256->10)
__global__ __launch_bounds__(256) void k_final(
    const float* __restrict__ IN, float* __restrict__ OUT,
    const float* __restrict__ w1v, const float* __restrict__ b1v,
    const float* __restrict__ w1t, const float* __restrict__ b1t,
    const float* __restrict__ w2t, const float* __restrict__ b2t)
{
    int blk = blockIdx.x;            // b*256 + n
    int m = threadIdx.x;
    int b = blk >> 8, n = blk & 255;
    const float* inp = IN + (size_t)(b*96) * 65536 + n * 256 + m;

    float Avo[32][3];
#pragma unroll
    for (int c = 0; c < 32; c++) {
        float f0 = inp[(size_t)(c*3 + 0) * 65536];
        float f1 = inp[(size_t)(c*3 + 1) * 65536];
        float f2 = inp[(size_t)(c*3 + 2) * 65536];
#pragma unroll
        for (int vo = 0; vo < 3; vo++)
            Avo[c][vo] = geluf(f0*w1v[vo] + f1*w1v[3 + vo] + f2*w1v[6 + vo] + b1v[vo]);
    }

    float acc2[3][10];
#pragma unroll
    for (int vo = 0; vo < 3; vo++)
#pragma unroll
        for (int s = 0; s < 10; s++) acc2[vo][s] = 0.f;

#pragma unroll 2
    for (int u = 0; u < 256; u++) {
        float t0 = b1t[u], t1 = t0, t2 = t0;
#pragma unroll
        for (int c = 0; c < 32; c++) {
            float wv = w1t[c*256 + u];
            t0 += Avo[c][0] * wv; t1 += Avo[c][1] * wv; t2 += Avo[c][2] * wv;
        }
        t0 = geluf(t0); t1 = geluf(t1); t2 = geluf(t2);
#pragma unroll
        for (int s = 0; s < 10; s++) {
            float wv = w2t[u*10 + s];
            acc2[0][s] += t0 * wv; acc2[1][s] += t1 * wv; acc2[2][s] += t2 * wv;
        }
    }

    float* outp = OUT + ((size_t)(b*3) * 65536 + n * 256 + m) * 10;
#pragma unroll
    for (int vo = 0; vo < 3; vo++)
#pragma unroll
        for (int s = 0; s < 10; s++)
            outp[(size_t)vo * 655360 + s] = acc2[vo][s] + b2t[s];
}

extern "C" void kernel_launch(void* const* d_in, const int* in_sizes, int n_in,
                              void* d_out, int out_size, void* d_ws, size_t ws_size,
                              hipStream_t stream) {
    const float* x    = (const float*)d_in[0];
    const float* fc0w = (const float*)d_in[1];
    const float* fc0b = (const float*)d_in[2];
    const float* w1r  = (const float*)d_in[3];
    const float* w1i  = (const float*)d_in[4];
    const float* w2r  = (const float*)d_in[5];
    const float* w2i  = (const float*)d_in[6];
    const float* m1w  = (const float*)d_in[7];
    const float* m1b  = (const float*)d_in[8];
    const float* m2w  = (const float*)d_in[9];
    const float* m2b  = (const float*)d_in[10];
    const float* ww   = (const float*)d_in[11];
    const float* wb   = (const float*)d_in[12];
    const float* bw   = (const float*)d_in[13];
    const float* bb   = (const float*)d_in[14];
    const float* w1v  = (const float*)d_in[15];
    const float* b1v  = (const float*)d_in[16];
    const float* w1t  = (const float*)d_in[17];
    const float* b1t  = (const float*)d_in[18];
    const float* w2t  = (const float*)d_in[19];
    const float* b2t  = (const float*)d_in[20];

    float* ws   = (float*)d_ws;
    float* A    = ws + OFF_A;
    float* Bu   = ws + OFF_B;
    float* T    = ws + OFF_T;     // reused as T2 after k_idft_x
    float* XF   = ws + OFF_XF;
    float* O    = ws + OFF_O;
    float* tab1 = ws + OFF_T1;
    float* tab2 = ws + OFF_T2T;
    float* tac  = ws + OFF_TAC;
    float* tas  = ws + OFF_TAS;
    float* tbB  = ws + OFF_TB;

    k_init_tables<<<64, 256, 0, stream>>>(ws);
    k_fc0<<<3072, 256, 0, stream>>>(x, fc0w, fc0b, A);

    // layer schedule: h0=L0(h) [A->A]; h=L1(h0) [A->B]; h=L2(h)+h0 [B->B, skip A];
    // h1=L3(h) [B->A]; h=L4(h1) [A->B]; h=L5(h)+h1 [B->B, skip A]
    float* lin [6] = {A, A, Bu, Bu, A, Bu};
    float* lout[6] = {A, Bu, Bu, A, Bu, Bu};
    const float* lskip[6] = {nullptr, nullptr, A, nullptr, nullptr, A};

    for (int l = 0; l < 6; l++) {
        k_dft_y<<<3072, 256, 0, stream>>>(lin[l], T, tab1);
        k_dft_x<<<384, 256, 0, stream>>>(T, XF, tab2);
        k_mix<<<384, 256, 0, stream>>>(XF, O, w1r, w1i, w2r, w2i, l);
        k_idft_x<<<384, 256, 0, stream>>>(O, T, tac, tas);
        if (lskip[l])
            k_conv<1><<<3072, 256, 0, stream>>>(lin[l], lout[l], lskip[l], T, tbB,
                                                m1w, m1b, m2w, m2b, ww, wb, bw, bb, l);
        else
            k_conv<0><<<3072, 256, 0, stream>>>(lin[l], lout[l], nullptr, T, tbB,
                                                m1w, m1b, m2w, m2b, ww, wb, bw, bb, l);
    }

    k_final<<<1024, 256, 0, stream>>>(Bu, (float*)d_out, w1v, b1v, w1t, b1t, w2t, b2t);
}

// Round 2
// 3215.397 us; speedup vs baseline: 1.2027x; 1.2027x over previous
//
#include <hip/hip_runtime.h>
#include <math.h>

// ---------------------------------------------------------------------------
// FNO_multi: B=4, V=3, S=256x256, TIN=10, WIDTH=32, M1=M2=16, NL=6, VOUT=3, STEP=10
// rfft2/irfft2 -> truncated DFT matmuls. All fp32.
// y-DFT fused into producer kernels (fc0/conv) via LDS row staging + radix-2 fold.
// Activations: [B][C=32][V][256][256].
// ---------------------------------------------------------------------------

#define OFF_A   0
#define OFF_B   25165824
#define OFF_T   50331648   // T / T2 shared buffer: [b,c,v,n] rows x 32 cols
#define OFF_XF  53477376
#define OFF_T1  54263808   // tabF [m=128][g=8][4]  (folded y-DFT tab, permuted groups)
#define OFF_T2T 54272000   // tab2 [n=256][kx=32][2] = (cos, sin)
#define OFF_TAC 54288384   // tabA_c [kx=32][n=256]
#define OFF_TAS 54296576   // tabA_s [kx=32][n=256]
#define OFF_TB  54304768   // tabB  [j=32][m=256]  (scaled inverse-y table)

__device__ __forceinline__ float geluf(float x) {
    return 0.5f * x * (1.0f + erff(x * 0.70710678118654752f));
}

__global__ void k_init_tables(float* __restrict__ ws) {
    const float W0 = 6.2831853071795864769f / 256.0f;
    int stride = gridDim.x * blockDim.x;
    int tid = blockIdx.x * blockDim.x + threadIdx.x;
    // tabF: folded forward y-DFT. group g: parity p=g>>2, idx=g&3; k0=4*idx+p, k1=k0+2
    for (int i = tid; i < 4096; i += stride) {
        int m = i >> 5, q = i & 31, g = q >> 2, j = q & 3;
        int k0 = 4 * (g & 3) + (g >> 2);
        int k = k0 + 2 * (j >> 1);
        float th = W0 * (float)((k * m) & 255);
        ws[OFF_T1 + i] = (j & 1) ? -sinf(th) : cosf(th);
    }
    for (int idx = tid; idx < 8192; idx += stride) {   // tab2
        int n = idx >> 5, kx = idx & 31;
        int KX = (kx < 16) ? kx : (kx + 224);
        float th = W0 * (float)((KX * n) & 255);
        ws[OFF_T2T + 2*idx]     = cosf(th);
        ws[OFF_T2T + 2*idx + 1] = sinf(th);
    }
    for (int idx = tid; idx < 8192; idx += stride) {   // tabA (inverse-x)
        int kx = idx >> 8, n = idx & 255;
        int KX = (kx < 16) ? kx : (kx + 224);
        float th = W0 * (float)((KX * n) & 255);
        ws[OFF_TAC + idx] = cosf(th);
        ws[OFF_TAS + idx] = sinf(th);
    }
    for (int idx = tid; idx < 8192; idx += stride) {   // tabB (inverse-y, scaled)
        int j = idx >> 8, m = idx & 255, k = j >> 1;
        float th = W0 * (float)((k * m) & 255);
        float beta = (k == 0) ? (1.0f/65536.0f) : (2.0f/65536.0f);
        float val;
        if (j & 1) val = (k == 0) ? 0.0f : -beta * sinf(th);
        else       val = beta * cosf(th);
        ws[OFF_TB + idx] = val;
    }
}

// radix-2 fold in LDS: row r: [0..127] <- e = x[m]+x[m+128]; [128..255] <- o = x[m]-x[m+128]
__device__ __forceinline__ void fold_lds(float* lds, int tid) {
#pragma unroll
    for (int it = 0; it < 16; ++it) {
        int pi = it * 256 + tid;
        int r = pi >> 7, mm = pi & 127;
        float* row = lds + r * 257;
        float a = row[mm], c = row[mm + 128];
        row[mm] = a + c; row[mm + 128] = a - c;
    }
}

// fused y-DFT phase: lds holds 32 folded rows (stride 257). Writes T rows (b,r,v,n), orig col order.
__device__ __forceinline__ void dft_row_phase(const float* lds, const float* __restrict__ tabF,
                                              float* __restrict__ T, int b, int v, int n, int tid) {
    int r = tid >> 3, g = tid & 7;
    int p = g >> 2, idx = g & 3;
    const float* dp = lds + r * 257 + p * 128;
    const float* tp = tabF + g * 4;
    float a0 = 0.f, a1 = 0.f, a2 = 0.f, a3 = 0.f;
#pragma unroll 4
    for (int m = 0; m < 128; ++m) {
        float d = dp[m];
        float4 t = *(const float4*)(tp + m * 32);
        a0 += d * t.x; a1 += d * t.y; a2 += d * t.z; a3 += d * t.w;
    }
    size_t trow = ((size_t)((b * 32 + r) * 3 + v) * 256 + n) * 32;
    float2 w0; w0.x = a0; w0.y = a1;
    float2 w1; w1.x = a2; w1.y = a3;
    *(float2*)(T + trow + 8 * idx + 2 * p) = w0;      // k0 = 4*idx+p (cols 2k0,2k0+1)
    *(float2*)(T + trow + 8 * idx + 2 * p + 4) = w1;  // k1 = k0+2
}

// fc0 + fused y-DFT
__global__ __launch_bounds__(256) void k_fc0(const float* __restrict__ x,
                                             const float* __restrict__ w,
                                             const float* __restrict__ bias,
                                             float* __restrict__ outA,
                                             float* __restrict__ T,
                                             const float* __restrict__ tabF) {
    __shared__ float lds[32 * 257];
    int blk = blockIdx.x;           // (b*3+v)*256 + n
    int m = threadIdx.x;
    int n = blk & 255;
    int bv = blk >> 8;
    int v = bv % 3, b = bv / 3;
    const float* xp = x + ((size_t)blk * 256 + m) * 10;
    float xin[10];
#pragma unroll
    for (int t = 0; t < 10; t++) xin[t] = xp[t];
    float gx = (float)n * (1.0f/255.0f), gy = (float)m * (1.0f/255.0f);
    float* op = outA + ((size_t)(b*96) + v) * 65536 + n * 256 + m;
#pragma unroll
    for (int c = 0; c < 32; c++) {
        float a = bias[c] + gx * w[10*32 + c] + gy * w[11*32 + c];
#pragma unroll
        for (int t = 0; t < 10; t++) a += xin[t] * w[t*32 + c];
        op[(size_t)c * 196608] = a;
        lds[c * 257 + m] = a;
    }
    __syncthreads();
    fold_lds(lds, m);
    __syncthreads();
    dft_row_phase(lds, tabF, T, b, v, n, m);
}

// x-DFT, T slab staged through LDS (coalesced)
__global__ __launch_bounds__(256) void k_dft_x(const float* __restrict__ T,
                                               float* __restrict__ XF,
                                               const float* __restrict__ tab2) {
    __shared__ float lds[8192];
    int blk = blockIdx.x;            // bv*32 + i
    int i = blk & 31; int bv = blk >> 5;
    int b = bv / 3, v = bv - 3*b;
    int tid = threadIdx.x;
    const float4* slab = (const float4*)(T + (size_t)((b*32 + i)*3 + v) * 8192);
#pragma unroll
    for (int j = 0; j < 8; ++j)
        ((float4*)lds)[j * 256 + tid] = slab[j * 256 + tid];
    __syncthreads();
    int ky = tid & 15, kxh = tid >> 4;
    float r0=0.f, i0=0.f, r1=0.f, i1=0.f;
#pragma unroll 2
    for (int n = 0; n < 256; n++) {
        float2 t = *(const float2*)(lds + n * 32 + 2 * ky);
        float2 cs0 = *(const float2*)(tab2 + n*64 + kxh*2);
        float2 cs1 = *(const float2*)(tab2 + n*64 + (kxh+16)*2);
        r0 += t.x*cs0.x + t.y*cs0.y;  i0 += t.y*cs0.x - t.x*cs0.y;
        r1 += t.x*cs1.x + t.y*cs1.y;  i1 += t.y*cs1.x - t.x*cs1.y;
    }
    float2* xfp = (float2*)(XF + (size_t)blk * 1024);
    float2 v0; v0.x = r0; v0.y = i0;
    float2 v1; v1.x = r1; v1.y = i1;
    xfp[kxh*16 + ky] = v0;
    xfp[(kxh+16)*16 + ky] = v1;
}

// complex channel mix + inverse x-DFT fused via LDS O-tile
__global__ __launch_bounds__(256) void k_mixidft(const float* __restrict__ XF,
                                                 float* __restrict__ T2,
                                                 const float* __restrict__ w1r,
                                                 const float* __restrict__ w1i,
                                                 const float* __restrict__ w2r,
                                                 const float* __restrict__ w2i,
                                                 const float* __restrict__ tac,
                                                 const float* __restrict__ tas, int l) {
    __shared__ float Olds[2048];
    int blk = blockIdx.x;            // bv*32 + o
    int o = blk & 31; int bv = blk >> 5;
    int b = bv / 3, v = bv - 3*b;
    int tid = threadIdx.x;
    {
        int ky = tid & 15, kxh = tid >> 4;
        float R0=0.f, I0=0.f, R1=0.f, I1=0.f;
#pragma unroll
        for (int i = 0; i < 32; i++) {
            const float2* xfp = (const float2*)(XF + (size_t)(bv*32 + i) * 1024);
            float2 xf0 = xfp[kxh*16 + ky];
            float2 xf1 = xfp[(kxh+16)*16 + ky];
            size_t wbase = ((size_t)((l*32 + i)*32 + o)*3 + v) * 256;
            float a1r = w1r[wbase + kxh*16 + ky], a1i = w1i[wbase + kxh*16 + ky];
            float a2r = w2r[wbase + kxh*16 + ky], a2i = w2i[wbase + kxh*16 + ky];
            R0 += xf0.x*a1r - xf0.y*a1i;  I0 += xf0.x*a1i + xf0.y*a1r;
            R1 += xf1.x*a2r - xf1.y*a2i;  I1 += xf1.x*a2i + xf1.y*a2r;
        }
        float2 v0; v0.x = R0; v0.y = I0;
        float2 v1; v1.x = R1; v1.y = I1;
        ((float2*)Olds)[kxh*16 + ky] = v0;
        ((float2*)Olds)[(kxh+16)*16 + ky] = v1;
    }
    __syncthreads();
    {
        int ky2 = tid & 31, n8 = tid >> 5;
        int ky = ky2 >> 1, ri = ky2 & 1;
        float* t2p = T2 + (size_t)((b*32 + o)*3 + v) * 8192;
#pragma unroll 2
        for (int ii = 0; ii < 32; ++ii) {
            int n = ii*8 + n8;
            float acc = 0.f;
#pragma unroll
            for (int kx = 0; kx < 32; ++kx) {
                float2 ov = ((const float2*)Olds)[kx*16 + ky];
                float c = tac[kx*256 + n], s = tas[kx*256 + n];
                float ca = ri ? s : c;
                float cb = ri ? c : -s;
                acc += ov.x*ca + ov.y*cb;
            }
            t2p[n*32 + ky2] = acc;
        }
    }
}

// fused: inverse y-DFT (from T2) + conv block + optional skip + fused NEXT-layer y-DFT.
// Block = (b,v,n) row; thread = column m. In-place T rewrite is per-row safe:
// all T reads (x1 phase) complete before the post-__syncthreads T writes.
template<int HAS_SKIP, int DO_DFT>
__global__ __launch_bounds__(256) void k_conv(
    const float* IN, float* OUT, const float* SK,
    const float* __restrict__ T2, const float* __restrict__ tabB,
    const float* __restrict__ m1w, const float* __restrict__ m1b,
    const float* __restrict__ m2w, const float* __restrict__ m2b,
    const float* __restrict__ ww,  const float* __restrict__ wb,
    const float* __restrict__ bw,  const float* __restrict__ bb,
    float* __restrict__ Tout, const float* __restrict__ tabF, int l)
{
    __shared__ float lds[32 * 257];
    int blk = blockIdx.x;            // (b*3+v)*256 + n
    int m = threadIdx.x;
    int n = blk & 255; int bv = blk >> 8;
    int b = bv / 3, v = bv - 3*b;

    // ---- inverse y-DFT: x1[c] = sum_j T2[b,c,v,n,j] * tabB[j][m]
    float tb[32];
#pragma unroll
    for (int j = 0; j < 32; j++) tb[j] = tabB[j*256 + m];
    const float* t2p = T2 + (size_t)(b*96 + v) * 8192 + n * 32;
    float x1[32];
#pragma unroll
    for (int c = 0; c < 32; c++) {
        const float* tp = t2p + c * 24576;
        float a = 0.f;
#pragma unroll
        for (int j = 0; j < 32; j++) a += tp[j] * tb[j];
        x1[c] = a;
    }

    // ---- conv m1 + gelu
    const float* m1wl = m1w + l*1024; const float* m1bl = m1b + l*32;
    float g1[32];
#pragma unroll
    for (int o = 0; o < 32; o++) {
        float a = m1bl[o];
#pragma unroll
        for (int c = 0; c < 32; c++) a += m1wl[o*32 + c] * x1[c];
        g1[o] = geluf(a);
    }

    // ---- load h (x2 path)
    const float* inp = IN + (size_t)(b*96 + v) * 65536 + n * 256 + m;
    float hv[32];
#pragma unroll
    for (int c = 0; c < 32; c++) hv[c] = inp[(size_t)c * 196608];

    const float* m2wl = m2w + l*1024; const float* m2bl = m2b + l*32;
    const float* wwl  = ww  + l*1024; const float* wbl  = wb  + l*32;
    const float* bwl  = bw  + l*64;   const float* bbl  = bb  + l*32;
    float gx = (float)n * (1.0f/255.0f), gy = (float)m * (1.0f/255.0f);
    float* outp = OUT + (size_t)(b*96 + v) * 65536 + n * 256 + m;
    const float* skp = SK + (size_t)(b*96 + v) * 65536 + n * 256 + m;

#pragma unroll
    for (int o = 0; o < 32; o++) {
        float a = m2bl[o] + wbl[o] + bbl[o] + bwl[o*2]*gx + bwl[o*2+1]*gy;
#pragma unroll
        for (int c = 0; c < 32; c++) a += m2wl[o*32 + c] * g1[c];
#pragma unroll
        for (int c = 0; c < 32; c++) a += wwl[o*32 + c] * hv[c];
        float val = geluf(a);
        if (HAS_SKIP) val += skp[(size_t)o * 196608];
        outp[(size_t)o * 196608] = val;
        if (DO_DFT) lds[o * 257 + m] = val;
    }
    if (DO_DFT) {
        __syncthreads();
        fold_lds(lds, m);
        __syncthreads();
        dft_row_phase(lds, tabF, Tout, b, v, n, m);
    }
}

// final: fc1v (v->vout, gelu) -> fc1t (32->256, gelu) -> fc2t (256->10)
// split per (b, n, vo): Avo shrinks to [32], VGPR/occupancy fix.
__global__ __launch_bounds__(256) void k_final(
    const float* __restrict__ IN, float* __restrict__ OUT,
    const float* __restrict__ w1v, const float* __restrict__ b1v,
    const float* __restrict__ w1t, const float* __restrict__ b1t,
    const float* __restrict__ w2t, const float* __restrict__ b2t)
{
    int blk = blockIdx.x;            // (b*256 + n)*3 + vo
    int m = threadIdx.x;
    int vo = blk % 3; int rest = blk / 3;
    int n = rest & 255, b = rest >> 8;
    const float* inp = IN + (size_t)(b*96) * 65536 + n * 256 + m;

    float wv0 = w1v[vo], wv1 = w1v[3 + vo], wv2 = w1v[6 + vo], bv0 = b1v[vo];
    float Av[32];
#pragma unroll
    for (int c = 0; c < 32; c++) {
        float f0 = inp[(size_t)(c*3 + 0) * 65536];
        float f1 = inp[(size_t)(c*3 + 1) * 65536];
        float f2 = inp[(size_t)(c*3 + 2) * 65536];
        Av[c] = geluf(f0*wv0 + f1*wv1 + f2*wv2 + bv0);
    }

    float acc[10];
#pragma unroll
    for (int s = 0; s < 10; s++) acc[s] = 0.f;

#pragma unroll 4
    for (int u = 0; u < 256; u++) {
        float t = b1t[u];
#pragma unroll
        for (int c = 0; c < 32; c++) t += Av[c] * w1t[c*256 + u];
        t = geluf(t);
#pragma unroll
        for (int s = 0; s < 10; s++) acc[s] += t * w2t[u*10 + s];
    }

    float* outp = OUT + ((size_t)(b*3 + vo) * 65536 + (size_t)(n * 256 + m)) * 10;
#pragma unroll
    for (int s = 0; s < 10; s++) outp[s] = acc[s] + b2t[s];
}

extern "C" void kernel_launch(void* const* d_in, const int* in_sizes, int n_in,
                              void* d_out, int out_size, void* d_ws, size_t ws_size,
                              hipStream_t stream) {
    const float* x    = (const float*)d_in[0];
    const float* fc0w = (const float*)d_in[1];
    const float* fc0b = (const float*)d_in[2];
    const float* w1r  = (const float*)d_in[3];
    const float* w1i  = (const float*)d_in[4];
    const float* w2r  = (const float*)d_in[5];
    const float* w2i  = (const float*)d_in[6];
    const float* m1w  = (const float*)d_in[7];
    const float* m1b  = (const float*)d_in[8];
    const float* m2w  = (const float*)d_in[9];
    const float* m2b  = (const float*)d_in[10];
    const float* ww   = (const float*)d_in[11];
    const float* wb   = (const float*)d_in[12];
    const float* bw   = (const float*)d_in[13];
    const float* bb   = (const float*)d_in[14];
    const float* w1v  = (const float*)d_in[15];
    const float* b1v  = (const float*)d_in[16];
    const float* w1t  = (const float*)d_in[17];
    const float* b1t  = (const float*)d_in[18];
    const float* w2t  = (const float*)d_in[19];
    const float* b2t  = (const float*)d_in[20];

    float* ws   = (float*)d_ws;
    float* A    = ws + OFF_A;
    float* Bu   = ws + OFF_B;
    float* T    = ws + OFF_T;
    float* XF   = ws + OFF_XF;
    float* tabF = ws + OFF_T1;
    float* tab2 = ws + OFF_T2T;
    float* tac  = ws + OFF_TAC;
    float* tas  = ws + OFF_TAS;
    float* tbB  = ws + OFF_TB;

    k_init_tables<<<64, 256, 0, stream>>>(ws);
    k_fc0<<<3072, 256, 0, stream>>>(x, fc0w, fc0b, A, T, tabF);

    // h0=L0(h) [A->A]; h=L1(h0) [A->B]; h=L2(h)+h0 [B->B, skip A];
    // h1=L3(h) [B->A]; h=L4(h1) [A->B]; h=L5(h)+h1 [B->B, skip A]
    float* lin [6] = {A, A, Bu, Bu, A, Bu};
    float* lout[6] = {A, Bu, Bu, A, Bu, Bu};
    const float* lskip[6] = {nullptr, nullptr, A, nullptr, nullptr, A};

    for (int l = 0; l < 6; l++) {
        k_dft_x<<<384, 256, 0, stream>>>(T, XF, tab2);
        k_mixidft<<<384, 256, 0, stream>>>(XF, T, w1r, w1i, w2r, w2i, tac, tas, l);
        int skip = lskip[l] != nullptr, dodft = (l < 5);
        if (skip && dodft)
            k_conv<1,1><<<3072, 256, 0, stream>>>(lin[l], lout[l], lskip[l], T, tbB,
                                                  m1w, m1b, m2w, m2b, ww, wb, bw, bb, T, tabF, l);
        else if (!skip && dodft)
            k_conv<0,1><<<3072, 256, 0, stream>>>(lin[l], lout[l], nullptr, T, tbB,
                                                  m1w, m1b, m2w, m2b, ww, wb, bw, bb, T, tabF, l);
        else if (skip && !dodft)
            k_conv<1,0><<<3072, 256, 0, stream>>>(lin[l], lout[l], lskip[l], T, tbB,
                                                  m1w, m1b, m2w, m2b, ww, wb, bw, bb, T, tabF, l);
        else
            k_conv<0,0><<<3072, 256, 0, stream>>>(lin[l], lout[l], nullptr, T, tbB,
                                                  m1w, m1b, m2w, m2b, ww, wb, bw, bb, T, tabF, l);
    }

    k_final<<<3072, 256, 0, stream>>>(Bu, (float*)d_out, w1v, b1v, w1t, b1t, w2t, b2t);
}

// Round 4
// 2542.166 us; speedup vs baseline: 1.5213x; 1.2648x over previous
//
#include <hip/hip_runtime.h>
#include <math.h>

// ---------------------------------------------------------------------------
// FNO_multi: B=4, V=3, S=256x256, TIN=10, WIDTH=32, M1=M2=16, NL=6, VOUT=3, STEP=10
// rfft2/irfft2 -> truncated DFT matmuls. All fp32.
// y-DFT fused into producer kernels (fc0/conv) via LDS row staging + radix-2 fold.
// Activations: [B][C=32][V][256][256].
// ---------------------------------------------------------------------------

#define OFF_A   0
#define OFF_B   25165824
#define OFF_T   50331648   // T / T2 shared buffer: [b,c,v,n] rows x 32 cols
#define OFF_XF  53477376   // 2 partial XF buffers, 393216 floats each
#define OFF_T1  54263808   // tabF [m=128][g=8][4]  (folded y-DFT tab, permuted groups)
#define OFF_T2T 54272000   // tab2 [n=256][kx=32][2] = (cos, sin)
#define OFF_TAC 54288384   // tabA_c [kx=32][n=256]
#define OFF_TAS 54296576   // tabA_s [kx=32][n=256]
#define OFF_TB  54304768   // tabB  [j=32][m=256]  (scaled inverse-y table)

// fast gelu: exact-erf form via A&S 7.1.26 (|eps_erf| <= ~1.5e-7)
__device__ __forceinline__ float geluf(float x) {
    float a = fabsf(x) * 0.70710678118654752f;
    float t = 1.0f / fmaf(0.3275911f, a, 1.0f);
    float p = t * fmaf(t, fmaf(t, fmaf(t, fmaf(t, 1.061405429f, -1.453152027f),
                                       1.421413741f), -0.284496736f), 0.254829592f);
    float e = __expf(-a * a);
    float erfa = fmaf(-p, e, 1.0f);      // erf(|z|)
    float er = copysignf(erfa, x);
    return 0.5f * x * (1.0f + er);
}

__global__ void k_init_tables(float* __restrict__ ws) {
    const float W0 = 6.2831853071795864769f / 256.0f;
    int stride = gridDim.x * blockDim.x;
    int tid = blockIdx.x * blockDim.x + threadIdx.x;
    // tabF: folded forward y-DFT. group g: parity p=g>>2, idx=g&3; k0=4*idx+p, k1=k0+2
    for (int i = tid; i < 4096; i += stride) {
        int m = i >> 5, q = i & 31, g = q >> 2, j = q & 3;
        int k0 = 4 * (g & 3) + (g >> 2);
        int k = k0 + 2 * (j >> 1);
        float th = W0 * (float)((k * m) & 255);
        ws[OFF_T1 + i] = (j & 1) ? -sinf(th) : cosf(th);
    }
    for (int idx = tid; idx < 8192; idx += stride) {   // tab2
        int n = idx >> 5, kx = idx & 31;
        int KX = (kx < 16) ? kx : (kx + 224);
        float th = W0 * (float)((KX * n) & 255);
        ws[OFF_T2T + 2*idx]     = cosf(th);
        ws[OFF_T2T + 2*idx + 1] = sinf(th);
    }
    for (int idx = tid; idx < 8192; idx += stride) {   // tabA (inverse-x)
        int kx = idx >> 8, n = idx & 255;
        int KX = (kx < 16) ? kx : (kx + 224);
        float th = W0 * (float)((KX * n) & 255);
        ws[OFF_TAC + idx] = cosf(th);
        ws[OFF_TAS + idx] = sinf(th);
    }
    for (int idx = tid; idx < 8192; idx += stride) {   // tabB (inverse-y, scaled)
        int j = idx >> 8, m = idx & 255, k = j >> 1;
        float th = W0 * (float)((k * m) & 255);
        float beta = (k == 0) ? (1.0f/65536.0f) : (2.0f/65536.0f);
        float val;
        if (j & 1) val = (k == 0) ? 0.0f : -beta * sinf(th);
        else       val = beta * cosf(th);
        ws[OFF_TB + idx] = val;
    }
}

// radix-2 fold in LDS: row r: [0..127] <- x[m]+x[m+128]; [128..255] <- x[m]-x[m+128]
__device__ __forceinline__ void fold_lds(float* lds, int tid) {
#pragma unroll
    for (int it = 0; it < 16; ++it) {
        int pi = it * 256 + tid;
        int r = pi >> 7, mm = pi & 127;
        float* row = lds + r * 257;
        float a = row[mm], c = row[mm + 128];
        row[mm] = a + c; row[mm + 128] = a - c;
    }
}

// fused y-DFT phase: lds holds 32 folded rows (stride 257). Writes T rows (b,r,v,n).
__device__ __forceinline__ void dft_row_phase(const float* lds, const float* __restrict__ tabF,
                                              float* __restrict__ T, int b, int v, int n, int tid) {
    int r = tid >> 3, g = tid & 7;
    int p = g >> 2, idx = g & 3;
    const float* dp = lds + r * 257 + p * 128;
    const float* tp = tabF + g * 4;
    float a0 = 0.f, a1 = 0.f, a2 = 0.f, a3 = 0.f;
#pragma unroll 4
    for (int m = 0; m < 128; ++m) {
        float d = dp[m];
        float4 t = *(const float4*)(tp + m * 32);
        a0 += d * t.x; a1 += d * t.y; a2 += d * t.z; a3 += d * t.w;
    }
    size_t trow = ((size_t)((b * 32 + r) * 3 + v) * 256 + n) * 32;
    float2 w0; w0.x = a0; w0.y = a1;
    float2 w1; w1.x = a2; w1.y = a3;
    *(float2*)(T + trow + 8 * idx + 2 * p) = w0;      // k0 = 4*idx+p
    *(float2*)(T + trow + 8 * idx + 2 * p + 4) = w1;  // k1 = k0+2
}

// fc0 + fused y-DFT
__global__ __launch_bounds__(256) void k_fc0(const float* __restrict__ x,
                                             const float* __restrict__ w,
                                             const float* __restrict__ bias,
                                             float* __restrict__ outA,
                                             float* __restrict__ T,
                                             const float* __restrict__ tabF) {
    __shared__ float lds[32 * 257];
    int blk = blockIdx.x;           // (b*3+v)*256 + n
    int m = threadIdx.x;
    int n = blk & 255;
    int bv = blk >> 8;
    int v = bv % 3, b = bv / 3;
    const float* xp = x + ((size_t)blk * 256 + m) * 10;
    float xin[10];
#pragma unroll
    for (int t = 0; t < 10; t++) xin[t] = xp[t];
    float gx = (float)n * (1.0f/255.0f), gy = (float)m * (1.0f/255.0f);
    float* op = outA + ((size_t)(b*96) + v) * 65536 + n * 256 + m;
#pragma unroll
    for (int c = 0; c < 32; c++) {
        float a = bias[c] + gx * w[10*32 + c] + gy * w[11*32 + c];
#pragma unroll
        for (int t = 0; t < 10; t++) a += xin[t] * w[t*32 + c];
        op[(size_t)c * 196608] = a;
        lds[c * 257 + m] = a;
    }
    __syncthreads();
    fold_lds(lds, m);
    __syncthreads();
    dft_row_phase(lds, tabF, T, b, v, n, m);
}

// x-DFT, split 2-way over n. blk = half*? -> idx: half = idx&1, slab = idx>>1.
__global__ __launch_bounds__(256) void k_dft_x(const float* __restrict__ T,
                                               float* __restrict__ XFp,
                                               const float* __restrict__ tab2) {
    __shared__ float lds[4096];
    int idx = blockIdx.x;
    int half = idx & 1; int blk = idx >> 1;   // blk = bv*32 + i
    int i = blk & 31; int bv = blk >> 5;
    int b = bv / 3, v = bv - 3*b;
    int tid = threadIdx.x;
    const float4* slab = (const float4*)(T + (size_t)((b*32 + i)*3 + v) * 8192 + half * 4096);
#pragma unroll
    for (int j = 0; j < 4; ++j)
        ((float4*)lds)[j * 256 + tid] = slab[j * 256 + tid];
    __syncthreads();
    int ky = tid & 15, kxh = tid >> 4;
    const float* t2b = tab2 + half * 128 * 64;
    float r0=0.f, i0=0.f, r1=0.f, i1=0.f;
#pragma unroll 2
    for (int nn = 0; nn < 128; nn++) {
        float2 t = *(const float2*)(lds + nn * 32 + 2 * ky);
        float2 cs0 = *(const float2*)(t2b + nn*64 + kxh*2);
        float2 cs1 = *(const float2*)(t2b + nn*64 + (kxh+16)*2);
        r0 += t.x*cs0.x + t.y*cs0.y;  i0 += t.y*cs0.x - t.x*cs0.y;
        r1 += t.x*cs1.x + t.y*cs1.y;  i1 += t.y*cs1.x - t.x*cs1.y;
    }
    float2* xfp = (float2*)(XFp + (size_t)(half * 384 + blk) * 1024);
    float2 v0; v0.x = r0; v0.y = i0;
    float2 v1; v1.x = r1; v1.y = i1;
    xfp[kxh*16 + ky] = v0;
    xfp[(kxh+16)*16 + ky] = v1;
}

// channel mix (sums the 2 XF partials) + inverse x-DFT, split 2-way over n.
__global__ __launch_bounds__(256) void k_mixidft(const float* __restrict__ XFp,
                                                 float* __restrict__ T2,
                                                 const float* __restrict__ w1r,
                                                 const float* __restrict__ w1i,
                                                 const float* __restrict__ w2r,
                                                 const float* __restrict__ w2i,
                                                 const float* __restrict__ tac,
                                                 const float* __restrict__ tas, int l) {
    __shared__ float Olds[2048];
    int idx = blockIdx.x;
    int half = idx & 1; int blk = idx >> 1;   // blk = bv*32 + o
    int o = blk & 31; int bv = blk >> 5;
    int b = bv / 3, v = bv - 3*b;
    int tid = threadIdx.x;
    {
        int ky = tid & 15, kxh = tid >> 4;
        float R0=0.f, I0=0.f, R1=0.f, I1=0.f;
#pragma unroll
        for (int i = 0; i < 32; i++) {
            const float2* xa = (const float2*)(XFp + (size_t)(bv*32 + i) * 1024);
            const float2* xb = (const float2*)(XFp + (size_t)(384 + bv*32 + i) * 1024);
            float2 p0 = xa[kxh*16 + ky], q0 = xb[kxh*16 + ky];
            float2 p1 = xa[(kxh+16)*16 + ky], q1 = xb[(kxh+16)*16 + ky];
            float2 xf0; xf0.x = p0.x + q0.x; xf0.y = p0.y + q0.y;
            float2 xf1; xf1.x = p1.x + q1.x; xf1.y = p1.y + q1.y;
            size_t wbase = ((size_t)((l*32 + i)*32 + o)*3 + v) * 256;
            float a1r = w1r[wbase + tid], a1i = w1i[wbase + tid];
            float a2r = w2r[wbase + tid], a2i = w2i[wbase + tid];
            R0 += xf0.x*a1r - xf0.y*a1i;  I0 += xf0.x*a1i + xf0.y*a1r;
            R1 += xf1.x*a2r - xf1.y*a2i;  I1 += xf1.x*a2i + xf1.y*a2r;
        }
        float2 v0; v0.x = R0; v0.y = I0;
        float2 v1; v1.x = R1; v1.y = I1;
        ((float2*)Olds)[kxh*16 + ky] = v0;
        ((float2*)Olds)[(kxh+16)*16 + ky] = v1;
    }
    __syncthreads();
    {
        int ky2 = tid & 31, n8 = tid >> 5;
        int ky = ky2 >> 1, ri = ky2 & 1;
        float* t2p = T2 + (size_t)((b*32 + o)*3 + v) * 8192;
#pragma unroll 2
        for (int ii = 0; ii < 16; ++ii) {
            int n = half * 128 + ii*8 + n8;
            float acc = 0.f;
#pragma unroll
            for (int kx = 0; kx < 32; ++kx) {
                float2 ov = ((const float2*)Olds)[kx*16 + ky];
                float c = tac[kx*256 + n], s = tas[kx*256 + n];
                float ca = ri ? s : c;
                float cb = ri ? c : -s;
                acc += ov.x*ca + ov.y*cb;
            }
            t2p[n*32 + ky2] = acc;
        }
    }
}

// fused: inverse y-DFT (from T2) + conv block + optional skip + fused NEXT-layer y-DFT.
// Phases ordered for VGPR control: x1 (tb dies) -> issue hv loads -> g1 (x1 dies)
// -> per-o m2/ww reduce + gelu + store.
template<int HAS_SKIP, int DO_DFT>
__global__ __launch_bounds__(256) void k_conv(
    const float* IN, float* OUT, const float* SK,
    const float* __restrict__ T2, const float* __restrict__ tabB,
    const float* __restrict__ m1w, const float* __restrict__ m1b,
    const float* __restrict__ m2w, const float* __restrict__ m2b,
    const float* __restrict__ ww,  const float* __restrict__ wb,
    const float* __restrict__ bw,  const float* __restrict__ bb,
    float* __restrict__ Tout, const float* __restrict__ tabF, int l)
{
    __shared__ float lds[DO_DFT ? 32 * 257 : 1];
    int blk = blockIdx.x;            // (b*3+v)*256 + n
    int m = threadIdx.x;
    int n = blk & 255; int bv = blk >> 8;
    int b = bv / 3, v = bv - 3*b;

    // ---- Phase A: inverse y-DFT: x1[c] = sum_j T2[b,c,v,n,j] * tabB[j][m]
    float tb[32];
#pragma unroll
    for (int j = 0; j < 32; j++) tb[j] = tabB[j*256 + m];
    const float* t2p = T2 + (size_t)(b*96 + v) * 8192 + n * 32;
    float x1[32];
#pragma unroll
    for (int c = 0; c < 32; c++) {
        const float* tp = t2p + c * 24576;
        float a = 0.f;
#pragma unroll
        for (int j = 0; j < 32; j++) a = fmaf(tp[j], tb[j], a);
        x1[c] = a;
    }

    // ---- issue h loads (x2 path) early; latency hides under Phase B
    const float* inp = IN + (size_t)(b*96 + v) * 65536 + n * 256 + m;
    float hv[32];
#pragma unroll
    for (int c = 0; c < 32; c++) hv[c] = inp[(size_t)c * 196608];

    // ---- Phase B: m1 + gelu
    const float* m1wl = m1w + l*1024; const float* m1bl = m1b + l*32;
    float g1[32];
#pragma unroll
    for (int o = 0; o < 32; o++) {
        float a = m1bl[o];
#pragma unroll
        for (int c = 0; c < 32; c++) a = fmaf(m1wl[o*32 + c], x1[c], a);
        g1[o] = geluf(a);
    }

    // ---- Phase C: per-o m2.g1 + ww.hv + bias terms, gelu, store (+DFT stage)
    const float* m2wl = m2w + l*1024; const float* m2bl = m2b + l*32;
    const float* wwl  = ww  + l*1024; const float* wbl  = wb  + l*32;
    const float* bwl  = bw  + l*64;   const float* bbl  = bb  + l*32;
    float gx = (float)n * (1.0f/255.0f), gy = (float)m * (1.0f/255.0f);
    float* outp = OUT + (size_t)(b*96 + v) * 65536 + n * 256 + m;
    const float* skp = SK + (size_t)(b*96 + v) * 65536 + n * 256 + m;

#pragma unroll
    for (int o = 0; o < 32; o++) {
        float a = m2bl[o] + wbl[o] + bbl[o] + bwl[o*2]*gx + bwl[o*2+1]*gy;
#pragma unroll
        for (int c = 0; c < 32; c++) a = fmaf(m2wl[o*32 + c], g1[c], a);
#pragma unroll
        for (int c = 0; c < 32; c++) a = fmaf(wwl[o*32 + c], hv[c], a);
        float val = geluf(a);
        if (HAS_SKIP) val += skp[(size_t)o * 196608];
        outp[(size_t)o * 196608] = val;
        if (DO_DFT) lds[o * 257 + m] = val;
    }
    if (DO_DFT) {
        __syncthreads();
        fold_lds(lds, m);
        __syncthreads();
        dft_row_phase(lds, tabF, Tout, b, v, n, m);
    }
}

// final: fc1v (v->vout, gelu) -> fc1t (32->256, gelu) -> fc2t (256->10); per-vo split
__global__ __launch_bounds__(256) void k_final(
    const float* __restrict__ IN, float* __restrict__ OUT,
    const float* __restrict__ w1v, const float* __restrict__ b1v,
    const float* __restrict__ w1t, const float* __restrict__ b1t,
    const float* __restrict__ w2t, const float* __restrict__ b2t)
{
    int blk = blockIdx.x;            // (b*256 + n)*3 + vo
    int m = threadIdx.x;
    int vo = blk % 3; int rest = blk / 3;
    int n = rest & 255, b = rest >> 8;
    const float* inp = IN + (size_t)(b*96) * 65536 + n * 256 + m;

    float wv0 = w1v[vo], wv1 = w1v[3 + vo], wv2 = w1v[6 + vo], bv0 = b1v[vo];
    float Av[32];
#pragma unroll
    for (int c = 0; c < 32; c++) {
        float f0 = inp[(size_t)(c*3 + 0) * 65536];
        float f1 = inp[(size_t)(c*3 + 1) * 65536];
        float f2 = inp[(size_t)(c*3 + 2) * 65536];
        Av[c] = geluf(f0*wv0 + f1*wv1 + f2*wv2 + bv0);
    }

    float acc[10];
#pragma unroll
    for (int s = 0; s < 10; s++) acc[s] = 0.f;

#pragma unroll 4
    for (int u = 0; u < 256; u++) {
        float t = b1t[u];
#pragma unroll
        for (int c = 0; c < 32; c++) t = fmaf(Av[c], w1t[c*256 + u], t);
        t = geluf(t);
#pragma unroll
        for (int s = 0; s < 10; s++) acc[s] = fmaf(t, w2t[u*10 + s], acc[s]);
    }

    float* outp = OUT + ((size_t)(b*3 + vo) * 65536 + (size_t)(n * 256 + m)) * 10;
#pragma unroll
    for (int s = 0; s < 10; s++) outp[s] = acc[s] + b2t[s];
}

extern "C" void kernel_launch(void* const* d_in, const int* in_sizes, int n_in,
                              void* d_out, int out_size, void* d_ws, size_t ws_size,
                              hipStream_t stream) {
    const float* x    = (const float*)d_in[0];
    const float* fc0w = (const float*)d_in[1];
    const float* fc0b = (const float*)d_in[2];
    const float* w1r  = (const float*)d_in[3];
    const float* w1i  = (const float*)d_in[4];
    const float* w2r  = (const float*)d_in[5];
    const float* w2i  = (const float*)d_in[6];
    const float* m1w  = (const float*)d_in[7];
    const float* m1b  = (const float*)d_in[8];
    const float* m2w  = (const float*)d_in[9];
    const float* m2b  = (const float*)d_in[10];
    const float* ww   = (const float*)d_in[11];
    const float* wb   = (const float*)d_in[12];
    const float* bw   = (const float*)d_in[13];
    const float* bb   = (const float*)d_in[14];
    const float* w1v  = (const float*)d_in[15];
    const float* b1v  = (const float*)d_in[16];
    const float* w1t  = (const float*)d_in[17];
    const float* b1t  = (const float*)d_in[18];
    const float* w2t  = (const float*)d_in[19];
    const float* b2t  = (const float*)d_in[20];

    float* ws   = (float*)d_ws;
    float* A    = ws + OFF_A;
    float* Bu   = ws + OFF_B;
    float* T    = ws + OFF_T;
    float* XFp  = ws + OFF_XF;
    float* tabF = ws + OFF_T1;
    float* tab2 = ws + OFF_T2T;
    float* tac  = ws + OFF_TAC;
    float* tas  = ws + OFF_TAS;
    float* tbB  = ws + OFF_TB;

    k_init_tables<<<64, 256, 0, stream>>>(ws);
    k_fc0<<<3072, 256, 0, stream>>>(x, fc0w, fc0b, A, T, tabF);

    // h0=L0(h) [A->A]; h=L1(h0) [A->B]; h=L2(h)+h0 [B->B, skip A];
    // h1=L3(h) [B->A]; h=L4(h1) [A->B]; h=L5(h)+h1 [B->B, skip A]
    float* lin [6] = {A, A, Bu, Bu, A, Bu};
    float* lout[6] = {A, Bu, Bu, A, Bu, Bu};
    const float* lskip[6] = {nullptr, nullptr, A, nullptr, nullptr, A};

    for (int l = 0; l < 6; l++) {
        k_dft_x<<<768, 256, 0, stream>>>(T, XFp, tab2);
        k_mixidft<<<768, 256, 0, stream>>>(XFp, T, w1r, w1i, w2r, w2i, tac, tas, l);
        int skip = lskip[l] != nullptr, dodft = (l < 5);
        if (skip && dodft)
            k_conv<1,1><<<3072, 256, 0, stream>>>(lin[l], lout[l], lskip[l], T, tbB,
                                                  m1w, m1b, m2w, m2b, ww, wb, bw, bb, T, tabF, l);
        else if (!skip && dodft)
            k_conv<0,1><<<3072, 256, 0, stream>>>(lin[l], lout[l], nullptr, T, tbB,
                                                  m1w, m1b, m2w, m2b, ww, wb, bw, bb, T, tabF, l);
        else if (skip && !dodft)
            k_conv<1,0><<<3072, 256, 0, stream>>>(lin[l], lout[l], lskip[l], T, tbB,
                                                  m1w, m1b, m2w, m2b, ww, wb, bw, bb, T, tabF, l);
        else
            k_conv<0,0><<<3072, 256, 0, stream>>>(lin[l], lout[l], nullptr, T, tbB,
                                                  m1w, m1b, m2w, m2b, ww, wb, bw, bb, T, tabF, l);
    }

    k_final<<<3072, 256, 0, stream>>>(Bu, (float*)d_out, w1v, b1v, w1t, b1t, w2t, b2t);
}

// Round 5
// 2464.477 us; speedup vs baseline: 1.5692x; 1.0315x over previous
//
#include <hip/hip_runtime.h>
#include <math.h>

// ---------------------------------------------------------------------------
// FNO_multi: B=4, V=3, S=256x256, TIN=10, WIDTH=32, M1=M2=16, NL=6, VOUT=3, STEP=10
// rfft2/irfft2 -> truncated DFT matmuls. All fp32.
// y-DFT fused into producer kernels (fc0/conv); m1 conv folded into spectral
// weights (W' = m1*W, exact linear-algebra reorder) when ws_size permits.
// Activations: [B][C=32][V][256][256].
// ---------------------------------------------------------------------------

#define OFF_A   0
#define OFF_B   25165824
#define OFF_T   50331648   // T / T2 shared buffer: [b,c,v,n] rows x 32 cols
#define OFF_XF  53477376   // 2 partial XF buffers, 393216 floats each
#define OFF_T1  54263808   // tabF [m=128][g=8][4]  (folded y-DFT tab, permuted groups)
#define OFF_T2T 54272000   // tab2 [n=256][kx=32][2] = (cos, sin)
#define OFF_TAC 54288384   // tabA_c [kx=32][n=256]
#define OFF_TAS 54296576   // tabA_s [kx=32][n=256]
#define OFF_TB  54304768   // tabB  [j=32][m=256]  (scaled inverse-y table)
#define OFF_FW  54312960   // folded weights: 4 x 4718592 floats (f1r,f1i,f2r,f2i)
#define FWSZ    4718592
#define WS_NEED_FOLD ((size_t)(OFF_FW + 4*FWSZ) * 4)

// fast gelu: exact-erf form via A&S 7.1.26 (|eps_erf| <= ~1.5e-7)
__device__ __forceinline__ float geluf(float x) {
    float a = fabsf(x) * 0.70710678118654752f;
    float t = __builtin_amdgcn_rcpf(fmaf(0.3275911f, a, 1.0f));
    float p = t * fmaf(t, fmaf(t, fmaf(t, fmaf(t, 1.061405429f, -1.453152027f),
                                       1.421413741f), -0.284496736f), 0.254829592f);
    float e = __expf(-a * a);
    float erfa = fmaf(-p, e, 1.0f);      // erf(|z|)
    float er = copysignf(erfa, x);
    return 0.5f * x * (1.0f + er);
}

__global__ void k_init_tables(float* __restrict__ ws) {
    const float W0 = 6.2831853071795864769f / 256.0f;
    int stride = gridDim.x * blockDim.x;
    int tid = blockIdx.x * blockDim.x + threadIdx.x;
    // tabF: folded forward y-DFT. group g: parity p=g>>2, idx=g&3; k0=4*idx+p, k1=k0+2
    for (int i = tid; i < 4096; i += stride) {
        int m = i >> 5, q = i & 31, g = q >> 2, j = q & 3;
        int k0 = 4 * (g & 3) + (g >> 2);
        int k = k0 + 2 * (j >> 1);
        float th = W0 * (float)((k * m) & 255);
        ws[OFF_T1 + i] = (j & 1) ? -sinf(th) : cosf(th);
    }
    for (int idx = tid; idx < 8192; idx += stride) {   // tab2
        int n = idx >> 5, kx = idx & 31;
        int KX = (kx < 16) ? kx : (kx + 224);
        float th = W0 * (float)((KX * n) & 255);
        ws[OFF_T2T + 2*idx]     = cosf(th);
        ws[OFF_T2T + 2*idx + 1] = sinf(th);
    }
    for (int idx = tid; idx < 8192; idx += stride) {   // tabA (inverse-x)
        int kx = idx >> 8, n = idx & 255;
        int KX = (kx < 16) ? kx : (kx + 224);
        float th = W0 * (float)((KX * n) & 255);
        ws[OFF_TAC + idx] = cosf(th);
        ws[OFF_TAS + idx] = sinf(th);
    }
    for (int idx = tid; idx < 8192; idx += stride) {   // tabB (inverse-y, scaled)
        int j = idx >> 8, m = idx & 255, k = j >> 1;
        float th = W0 * (float)((k * m) & 255);
        float beta = (k == 0) ? (1.0f/65536.0f) : (2.0f/65536.0f);
        float val;
        if (j & 1) val = (k == 0) ? 0.0f : -beta * sinf(th);
        else       val = beta * cosf(th);
        ws[OFF_TB + idx] = val;
    }
}

// fold m1 into spectral weights: F[l,i,o',v,p] = sum_o m1w[l,o',o] * W[l,i,o,v,p]
__global__ __launch_bounds__(256) void k_foldw(const float* __restrict__ w1r,
                                               const float* __restrict__ w1i,
                                               const float* __restrict__ w2r,
                                               const float* __restrict__ w2i,
                                               const float* __restrict__ m1w,
                                               float* __restrict__ f1r, float* __restrict__ f1i,
                                               float* __restrict__ f2r, float* __restrict__ f2i) {
    int blk = blockIdx.x;            // (l*32+i)*32 + op
    int p = threadIdx.x;
    int op = blk & 31; int li = blk >> 5;   // li = l*32+i
    int l = li >> 5;
    const float* mrow = m1w + l*1024 + op*32;
#pragma unroll
    for (int v = 0; v < 3; ++v) {
        float a1r = 0.f, a1i = 0.f, a2r = 0.f, a2i = 0.f;
#pragma unroll 4
        for (int o = 0; o < 32; ++o) {
            float mw = mrow[o];
            size_t idx = ((size_t)(li*32 + o)*3 + v)*256 + p;
            a1r = fmaf(mw, w1r[idx], a1r); a1i = fmaf(mw, w1i[idx], a1i);
            a2r = fmaf(mw, w2r[idx], a2r); a2i = fmaf(mw, w2i[idx], a2i);
        }
        size_t oidx = ((size_t)(li*32 + op)*3 + v)*256 + p;
        f1r[oidx] = a1r; f1i[oidx] = a1i; f2r[oidx] = a2r; f2i[oidx] = a2i;
    }
}

// radix-2 fold in LDS: row r: [0..127] <- x[m]+x[m+128]; [128..255] <- x[m]-x[m+128]
__device__ __forceinline__ void fold_lds(float* lds, int tid) {
#pragma unroll
    for (int it = 0; it < 16; ++it) {
        int pi = it * 256 + tid;
        int r = pi >> 7, mm = pi & 127;
        float* row = lds + r * 257;
        float a = row[mm], c = row[mm + 128];
        row[mm] = a + c; row[mm + 128] = a - c;
    }
}

// fused y-DFT phase: lds holds 32 folded rows (stride 257). Writes T rows (b,r,v,n).
__device__ __forceinline__ void dft_row_phase(const float* lds, const float* __restrict__ tabF,
                                              float* __restrict__ T, int b, int v, int n, int tid) {
    int r = tid >> 3, g = tid & 7;
    int p = g >> 2, idx = g & 3;
    const float* dp = lds + r * 257 + p * 128;
    const float* tp = tabF + g * 4;
    float a0 = 0.f, a1 = 0.f, a2 = 0.f, a3 = 0.f;
#pragma unroll 4
    for (int m = 0; m < 128; ++m) {
        float d = dp[m];
        float4 t = *(const float4*)(tp + m * 32);
        a0 += d * t.x; a1 += d * t.y; a2 += d * t.z; a3 += d * t.w;
    }
    size_t trow = ((size_t)((b * 32 + r) * 3 + v) * 256 + n) * 32;
    float2 w0; w0.x = a0; w0.y = a1;
    float2 w1; w1.x = a2; w1.y = a3;
    *(float2*)(T + trow + 8 * idx + 2 * p) = w0;      // k0 = 4*idx+p
    *(float2*)(T + trow + 8 * idx + 2 * p + 4) = w1;  // k1 = k0+2
}

// fc0 + fused y-DFT
__global__ __launch_bounds__(256) void k_fc0(const float* __restrict__ x,
                                             const float* __restrict__ w,
                                             const float* __restrict__ bias,
                                             float* __restrict__ outA,
                                             float* __restrict__ T,
                                             const float* __restrict__ tabF) {
    __shared__ float lds[32 * 257];
    int blk = blockIdx.x;           // (b*3+v)*256 + n
    int m = threadIdx.x;
    int n = blk & 255;
    int bv = blk >> 8;
    int v = bv % 3, b = bv / 3;
    const float* xp = x + ((size_t)blk * 256 + m) * 10;
    float xin[10];
#pragma unroll
    for (int t = 0; t < 10; t++) xin[t] = xp[t];
    float gx = (float)n * (1.0f/255.0f), gy = (float)m * (1.0f/255.0f);
    float* op = outA + ((size_t)(b*96) + v) * 65536 + n * 256 + m;
#pragma unroll
    for (int c = 0; c < 32; c++) {
        float a = bias[c] + gx * w[10*32 + c] + gy * w[11*32 + c];
#pragma unroll
        for (int t = 0; t < 10; t++) a += xin[t] * w[t*32 + c];
        op[(size_t)c * 196608] = a;
        lds[c * 257 + m] = a;
    }
    __syncthreads();
    fold_lds(lds, m);
    __syncthreads();
    dft_row_phase(lds, tabF, T, b, v, n, m);
}

// x-DFT, split 2-way over n.
__global__ __launch_bounds__(256) void k_dft_x(const float* __restrict__ T,
                                               float* __restrict__ XFp,
                                               const float* __restrict__ tab2) {
    __shared__ float lds[4096];
    int idx = blockIdx.x;
    int half = idx & 1; int blk = idx >> 1;   // blk = bv*32 + i
    int i = blk & 31; int bv = blk >> 5;
    int b = bv / 3, v = bv - 3*b;
    int tid = threadIdx.x;
    const float4* slab = (const float4*)(T + (size_t)((b*32 + i)*3 + v) * 8192 + half * 4096);
#pragma unroll
    for (int j = 0; j < 4; ++j)
        ((float4*)lds)[j * 256 + tid] = slab[j * 256 + tid];
    __syncthreads();
    int ky = tid & 15, kxh = tid >> 4;
    const float* t2b = tab2 + half * 128 * 64;
    float r0=0.f, i0=0.f, r1=0.f, i1=0.f;
#pragma unroll 2
    for (int nn = 0; nn < 128; nn++) {
        float2 t = *(const float2*)(lds + nn * 32 + 2 * ky);
        float2 cs0 = *(const float2*)(t2b + nn*64 + kxh*2);
        float2 cs1 = *(const float2*)(t2b + nn*64 + (kxh+16)*2);
        r0 += t.x*cs0.x + t.y*cs0.y;  i0 += t.y*cs0.x - t.x*cs0.y;
        r1 += t.x*cs1.x + t.y*cs1.y;  i1 += t.y*cs1.x - t.x*cs1.y;
    }
    float2* xfp = (float2*)(XFp + (size_t)(half * 384 + blk) * 1024);
    float2 v0; v0.x = r0; v0.y = i0;
    float2 v1; v1.x = r1; v1.y = i1;
    xfp[kxh*16 + ky] = v0;
    xfp[(kxh+16)*16 + ky] = v1;
}

// channel mix (sums the 2 XF partials) + inverse x-DFT, split 2-way over n.
// Weight pointers may be the folded (m1-premixed) arrays — identical layout.
__global__ __launch_bounds__(256) void k_mixidft(const float* __restrict__ XFp,
                                                 float* __restrict__ T2,
                                                 const float* __restrict__ w1r,
                                                 const float* __restrict__ w1i,
                                                 const float* __restrict__ w2r,
                                                 const float* __restrict__ w2i,
                                                 const float* __restrict__ tac,
                                                 const float* __restrict__ tas, int l) {
    __shared__ float Olds[2048];
    int idx = blockIdx.x;
    int half = idx & 1; int blk = idx >> 1;   // blk = bv*32 + o
    int o = blk & 31; int bv = blk >> 5;
    int b = bv / 3, v = bv - 3*b;
    int tid = threadIdx.x;
    {
        int ky = tid & 15, kxh = tid >> 4;
        float R0=0.f, I0=0.f, R1=0.f, I1=0.f;
#pragma unroll
        for (int i = 0; i < 32; i++) {
            const float2* xa = (const float2*)(XFp + (size_t)(bv*32 + i) * 1024);
            const float2* xb = (const float2*)(XFp + (size_t)(384 + bv*32 + i) * 1024);
            float2 p0 = xa[kxh*16 + ky], q0 = xb[kxh*16 + ky];
            float2 p1 = xa[(kxh+16)*16 + ky], q1 = xb[(kxh+16)*16 + ky];
            float2 xf0; xf0.x = p0.x + q0.x; xf0.y = p0.y + q0.y;
            float2 xf1; xf1.x = p1.x + q1.x; xf1.y = p1.y + q1.y;
            size_t wbase = ((size_t)((l*32 + i)*32 + o)*3 + v) * 256;
            float a1r = w1r[wbase + tid], a1i = w1i[wbase + tid];
            float a2r = w2r[wbase + tid], a2i = w2i[wbase + tid];
            R0 += xf0.x*a1r - xf0.y*a1i;  I0 += xf0.x*a1i + xf0.y*a1r;
            R1 += xf1.x*a2r - xf1.y*a2i;  I1 += xf1.x*a2i + xf1.y*a2r;
        }
        float2 v0; v0.x = R0; v0.y = I0;
        float2 v1; v1.x = R1; v1.y = I1;
        ((float2*)Olds)[kxh*16 + ky] = v0;
        ((float2*)Olds)[(kxh+16)*16 + ky] = v1;
    }
    __syncthreads();
    {
        int ky2 = tid & 31, n8 = tid >> 5;
        int ky = ky2 >> 1, ri = ky2 & 1;
        float* t2p = T2 + (size_t)((b*32 + o)*3 + v) * 8192;
#pragma unroll 2
        for (int ii = 0; ii < 16; ++ii) {
            int n = half * 128 + ii*8 + n8;
            float acc = 0.f;
#pragma unroll
            for (int kx = 0; kx < 32; ++kx) {
                float2 ov = ((const float2*)Olds)[kx*16 + ky];
                float c = tac[kx*256 + n], s = tas[kx*256 + n];
                float ca = ri ? s : c;
                float cb = ri ? c : -s;
                acc += ov.x*ca + ov.y*cb;
            }
            t2p[n*32 + ky2] = acc;
        }
    }
}

// fused: inverse y-DFT (from T2) + conv block + optional skip + fused NEXT-layer y-DFT.
// FOLDED: T2 is already m1-premixed (via folded spectral weights) -> g1 computed
// directly from T2, no x1 array, no m1 GEMM.
template<int HAS_SKIP, int DO_DFT, int FOLDED>
__global__ __launch_bounds__(256) void k_conv(
    const float* IN, float* OUT, const float* SK,
    const float* __restrict__ T2, const float* __restrict__ tabB,
    const float* __restrict__ m1w, const float* __restrict__ m1b,
    const float* __restrict__ m2w, const float* __restrict__ m2b,
    const float* __restrict__ ww,  const float* __restrict__ wb,
    const float* __restrict__ bw,  const float* __restrict__ bb,
    float* __restrict__ Tout, const float* __restrict__ tabF, int l)
{
    __shared__ float lds[DO_DFT ? 32 * 257 : 1];
    int blk = blockIdx.x;            // (b*3+v)*256 + n
    int m = threadIdx.x;
    int n = blk & 255; int bv = blk >> 8;
    int b = bv / 3, v = bv - 3*b;

    // ---- Phase A: inverse y-DFT (+ m1 if not folded), gelu -> g1
    float tb[32];
#pragma unroll
    for (int j = 0; j < 32; j++) tb[j] = tabB[j*256 + m];
    const float* t2p = T2 + (size_t)(b*96 + v) * 8192 + n * 32;
    const float* m1bl = m1b + l*32;
    float g1[32];
    if (FOLDED) {
#pragma unroll
        for (int o = 0; o < 32; o++) {
            const float* tp = t2p + o * 24576;
            float a = m1bl[o];
#pragma unroll
            for (int j = 0; j < 32; j++) a = fmaf(tp[j], tb[j], a);
            g1[o] = geluf(a);
        }
    } else {
        float x1[32];
#pragma unroll
        for (int c = 0; c < 32; c++) {
            const float* tp = t2p + c * 24576;
            float a = 0.f;
#pragma unroll
            for (int j = 0; j < 32; j++) a = fmaf(tp[j], tb[j], a);
            x1[c] = a;
        }
        const float* m1wl = m1w + l*1024;
#pragma unroll
        for (int o = 0; o < 32; o++) {
            float a = m1bl[o];
#pragma unroll
            for (int c = 0; c < 32; c++) a = fmaf(m1wl[o*32 + c], x1[c], a);
            g1[o] = geluf(a);
        }
    }

    // ---- h loads (x2 path); latency hides under Phase C lead-in
    const float* inp = IN + (size_t)(b*96 + v) * 65536 + n * 256 + m;
    float hv[32];
#pragma unroll
    for (int c = 0; c < 32; c++) hv[c] = inp[(size_t)c * 196608];

    // ---- Phase C: per-o m2.g1 + ww.hv + bias terms, gelu, store (+DFT stage)
    const float* m2wl = m2w + l*1024; const float* m2bl = m2b + l*32;
    const float* wwl  = ww  + l*1024; const float* wbl  = wb  + l*32;
    const float* bwl  = bw  + l*64;   const float* bbl  = bb  + l*32;
    float gx = (float)n * (1.0f/255.0f), gy = (float)m * (1.0f/255.0f);
    float* outp = OUT + (size_t)(b*96 + v) * 65536 + n * 256 + m;
    const float* skp = SK + (size_t)(b*96 + v) * 65536 + n * 256 + m;

#pragma unroll
    for (int o = 0; o < 32; o++) {
        float a = m2bl[o] + wbl[o] + bbl[o] + bwl[o*2]*gx + bwl[o*2+1]*gy;
#pragma unroll
        for (int c = 0; c < 32; c++) a = fmaf(m2wl[o*32 + c], g1[c], a);
#pragma unroll
        for (int c = 0; c < 32; c++) a = fmaf(wwl[o*32 + c], hv[c], a);
        float val = geluf(a);
        if (HAS_SKIP) val += skp[(size_t)o * 196608];
        outp[(size_t)o * 196608] = val;
        if (DO_DFT) lds[o * 257 + m] = val;
    }
    if (DO_DFT) {
        __syncthreads();
        fold_lds(lds, m);
        __syncthreads();
        dft_row_phase(lds, tabF, Tout, b, v, n, m);
    }
}

// final: fc1v (v->vout, gelu) -> fc1t (32->256, gelu) -> fc2t (256->10); per-vo split
__global__ __launch_bounds__(256) void k_final(
    const float* __restrict__ IN, float* __restrict__ OUT,
    const float* __restrict__ w1v, const float* __restrict__ b1v,
    const float* __restrict__ w1t, const float* __restrict__ b1t,
    const float* __restrict__ w2t, const float* __restrict__ b2t)
{
    int blk = blockIdx.x;            // (b*256 + n)*3 + vo
    int m = threadIdx.x;
    int vo = blk % 3; int rest = blk / 3;
    int n = rest & 255, b = rest >> 8;
    const float* inp = IN + (size_t)(b*96) * 65536 + n * 256 + m;

    float wv0 = w1v[vo], wv1 = w1v[3 + vo], wv2 = w1v[6 + vo], bv0 = b1v[vo];
    float Av[32];
#pragma unroll
    for (int c = 0; c < 32; c++) {
        float f0 = inp[(size_t)(c*3 + 0) * 65536];
        float f1 = inp[(size_t)(c*3 + 1) * 65536];
        float f2 = inp[(size_t)(c*3 + 2) * 65536];
        Av[c] = geluf(f0*wv0 + f1*wv1 + f2*wv2 + bv0);
    }

    float acc[10];
#pragma unroll
    for (int s = 0; s < 10; s++) acc[s] = 0.f;

#pragma unroll 4
    for (int u = 0; u < 256; u++) {
        float t = b1t[u];
#pragma unroll
        for (int c = 0; c < 32; c++) t = fmaf(Av[c], w1t[c*256 + u], t);
        t = geluf(t);
#pragma unroll
        for (int s = 0; s < 10; s++) acc[s] = fmaf(t, w2t[u*10 + s], acc[s]);
    }

    float* outp = OUT + ((size_t)(b*3 + vo) * 65536 + (size_t)(n * 256 + m)) * 10;
#pragma unroll
    for (int s = 0; s < 10; s++) outp[s] = acc[s] + b2t[s];
}

extern "C" void kernel_launch(void* const* d_in, const int* in_sizes, int n_in,
                              void* d_out, int out_size, void* d_ws, size_t ws_size,
                              hipStream_t stream) {
    const float* x    = (const float*)d_in[0];
    const float* fc0w = (const float*)d_in[1];
    const float* fc0b = (const float*)d_in[2];
    const float* w1r  = (const float*)d_in[3];
    const float* w1i  = (const float*)d_in[4];
    const float* w2r  = (const float*)d_in[5];
    const float* w2i  = (const float*)d_in[6];
    const float* m1w  = (const float*)d_in[7];
    const float* m1b  = (const float*)d_in[8];
    const float* m2w  = (const float*)d_in[9];
    const float* m2b  = (const float*)d_in[10];
    const float* ww   = (const float*)d_in[11];
    const float* wb   = (const float*)d_in[12];
    const float* bw   = (const float*)d_in[13];
    const float* bb   = (const float*)d_in[14];
    const float* w1v  = (const float*)d_in[15];
    const float* b1v  = (const float*)d_in[16];
    const float* w1t  = (const float*)d_in[17];
    const float* b1t  = (const float*)d_in[18];
    const float* w2t  = (const float*)d_in[19];
    const float* b2t  = (const float*)d_in[20];

    float* ws   = (float*)d_ws;
    float* A    = ws + OFF_A;
    float* Bu   = ws + OFF_B;
    float* T    = ws + OFF_T;
    float* XFp  = ws + OFF_XF;
    float* tabF = ws + OFF_T1;
    float* tab2 = ws + OFF_T2T;
    float* tac  = ws + OFF_TAC;
    float* tas  = ws + OFF_TAS;
    float* tbB  = ws + OFF_TB;

    const bool fold = ws_size >= WS_NEED_FOLD;
    float* f1r = ws + OFF_FW;
    float* f1i = ws + OFF_FW + FWSZ;
    float* f2r = ws + OFF_FW + 2*FWSZ;
    float* f2i = ws + OFF_FW + 3*FWSZ;

    k_init_tables<<<64, 256, 0, stream>>>(ws);
    if (fold)
        k_foldw<<<6144, 256, 0, stream>>>(w1r, w1i, w2r, w2i, m1w, f1r, f1i, f2r, f2i);
    k_fc0<<<3072, 256, 0, stream>>>(x, fc0w, fc0b, A, T, tabF);

    const float* u1r = fold ? f1r : w1r;  const float* u1i = fold ? f1i : w1i;
    const float* u2r = fold ? f2r : w2r;  const float* u2i = fold ? f2i : w2i;

    // h0=L0(h) [A->A]; h=L1(h0) [A->B]; h=L2(h)+h0 [B->B, skip A];
    // h1=L3(h) [B->A]; h=L4(h1) [A->B]; h=L5(h)+h1 [B->B, skip A]
    float* lin [6] = {A, A, Bu, Bu, A, Bu};
    float* lout[6] = {A, Bu, Bu, A, Bu, Bu};
    const float* lskip[6] = {nullptr, nullptr, A, nullptr, nullptr, A};

    for (int l = 0; l < 6; l++) {
        k_dft_x<<<768, 256, 0, stream>>>(T, XFp, tab2);
        k_mixidft<<<768, 256, 0, stream>>>(XFp, T, u1r, u1i, u2r, u2i, tac, tas, l);
        int skip = lskip[l] != nullptr, dodft = (l < 5);
        if (fold) {
            if (skip && dodft)
                k_conv<1,1,1><<<3072, 256, 0, stream>>>(lin[l], lout[l], lskip[l], T, tbB,
                                                        m1w, m1b, m2w, m2b, ww, wb, bw, bb, T, tabF, l);
            else if (!skip && dodft)
                k_conv<0,1,1><<<3072, 256, 0, stream>>>(lin[l], lout[l], nullptr, T, tbB,
                                                        m1w, m1b, m2w, m2b, ww, wb, bw, bb, T, tabF, l);
            else if (skip && !dodft)
                k_conv<1,0,1><<<3072, 256, 0, stream>>>(lin[l], lout[l], lskip[l], T, tbB,
                                                        m1w, m1b, m2w, m2b, ww, wb, bw, bb, T, tabF, l);
            else
                k_conv<0,0,1><<<3072, 256, 0, stream>>>(lin[l], lout[l], nullptr, T, tbB,
                                                        m1w, m1b, m2w, m2b, ww, wb, bw, bb, T, tabF, l);
        } else {
            if (skip && dodft)
                k_conv<1,1,0><<<3072, 256, 0, stream>>>(lin[l], lout[l], lskip[l], T, tbB,
                                                        m1w, m1b, m2w, m2b, ww, wb, bw, bb, T, tabF, l);
            else if (!skip && dodft)
                k_conv<0,1,0><<<3072, 256, 0, stream>>>(lin[l], lout[l], nullptr, T, tbB,
                                                        m1w, m1b, m2w, m2b, ww, wb, bw, bb, T, tabF, l);
            else if (skip && !dodft)
                k_conv<1,0,0><<<3072, 256, 0, stream>>>(lin[l], lout[l], lskip[l], T, tbB,
                                                        m1w, m1b, m2w, m2b, ww, wb, bw, bb, T, tabF, l);
            else
                k_conv<0,0,0><<<3072, 256, 0, stream>>>(lin[l], lout[l], nullptr, T, tbB,
                                                        m1w, m1b, m2w, m2b, ww, wb, bw, bb, T, tabF, l);
        }
    }

    k_final<<<3072, 256, 0, stream>>>(Bu, (float*)d_out, w1v, b1v, w1t, b1t, w2t, b2t);
}